// Round 4
// baseline (937.639 us; speedup 1.0000x reference)
//
#include <hip/hip_runtime.h>
#include <hip/hip_fp16.h>

// LightGCN propagation on MI355X — round 4: bucketed CSR build.
// N = 100000 nodes, D = 128, E = 2,000,000 edges, 3 layers.
//
// Round-3 bottleneck: lgcn_fill's scattered 8 B stores to 100K row-tails
// (6.4 MB active line set > 4 MB per-XCD L2) -> 8x write amplification
// (124 MB for 16 MB payload), 157 us. Round 4 sorts in two phases:
//   phase 1 (bin): append edges to 782 row>>7 buckets. Active write set =
//     782 tail lines (~50 KB) -> L2 write-combining, near-1x amplification.
//     Edge packed to 8 B: ((row&127)<<17 | col, val_bits).
//   phase 2 (csr): one block per bucket; LDS hist of its 128 rows + wave
//     scan gives row_ptr directly (bucket output regions are contiguous ->
//     no global per-row histogram, no global scan), then scatters (col,val)
//     within the bucket's ~20 KB L2-hot output region.
// SpMM: fp16 gathers (one wave/row, 4 B/lane), unroll 8, non-temporal edge
// loads; layer 3 fuses out = (emb + x1 + x2 + A x2) * 0.25.

#define DIM 128
#define RPB 128        // rows per bucket
#define RPB_SHIFT 7

static inline size_t align_up(size_t v, size_t a) { return (v + a - 1) & ~(a - 1); }

__global__ void lgcn_conv(const float2* __restrict__ emb, __half2* __restrict__ x0,
                          int n2) {
    int i = blockIdx.x * blockDim.x + threadIdx.x;
    if (i < n2) x0[i] = __float22half2_rn(emb[i]);
}

// Bucket histogram with per-block LDS aggregation.
__global__ void __launch_bounds__(256)
lgcn_bhist(const int* __restrict__ rows, int* __restrict__ bcnt,
           int nedges, int nb) {
    __shared__ int h[1024];
    for (int i = threadIdx.x; i < nb; i += 256) h[i] = 0;
    __syncthreads();
    for (int e = blockIdx.x * 256 + threadIdx.x; e < nedges; e += gridDim.x * 256)
        atomicAdd(&h[rows[e] >> RPB_SHIFT], 1);
    __syncthreads();
    for (int i = threadIdx.x; i < nb; i += 256) {
        int v = h[i];
        if (v) atomicAdd(&bcnt[i], v);
    }
}

// Exclusive scan of bucket counts (nb <= 1024) in one 1024-thread block.
__global__ void __launch_bounds__(1024)
lgcn_bscan(const int* __restrict__ bcnt, int* __restrict__ bbase,
           int* __restrict__ bcursor, int* __restrict__ row_ptr,
           int nb, int n) {
    __shared__ int wsum[16];
    const int tid  = threadIdx.x;
    const int lane = tid & 63;
    const int wid  = tid >> 6;
    int v = (tid < nb) ? bcnt[tid] : 0;
    int incl = v;
    #pragma unroll
    for (int off = 1; off < 64; off <<= 1) {
        int t = __shfl_up(incl, off, 64);
        if (lane >= off) incl += t;
    }
    if (lane == 63) wsum[wid] = incl;
    __syncthreads();
    if (wid == 0 && lane < 16) {
        int w = wsum[lane];
        #pragma unroll
        for (int off = 1; off < 16; off <<= 1) {
            int t = __shfl_up(w, off, 64);
            if (lane >= off) w += t;
        }
        wsum[lane] = w;
    }
    __syncthreads();
    int ex = incl - v + ((wid > 0) ? wsum[wid - 1] : 0);
    if (tid < nb) {
        bbase[tid]   = ex;
        bcursor[tid] = ex;
        if (tid == nb - 1) {
            bbase[nb]  = ex + v;   // total = E
            row_ptr[n] = ex + v;
        }
    }
}

// Phase 1: append edges to buckets.
__global__ void lgcn_bin(const int* __restrict__ rows, const int* __restrict__ cols,
                         const float* __restrict__ vals, int* __restrict__ bcursor,
                         int2* __restrict__ binned, int nedges) {
    int e = blockIdx.x * blockDim.x + threadIdx.x;
    if (e < nedges) {
        int r = rows[e];
        int pos = atomicAdd(&bcursor[r >> RPB_SHIFT], 1);
        binned[pos] = make_int2(((r & (RPB - 1)) << 17) | cols[e],
                                __float_as_int(vals[e]));
    }
}

// Phase 2: one block per bucket -> row_ptr + row-sorted (col,val) edges.
__global__ void __launch_bounds__(256)
lgcn_csr(const int2* __restrict__ binned, const int* __restrict__ bbase,
         int* __restrict__ row_ptr, int2* __restrict__ edges, int n) {
    __shared__ int hist[RPB];
    __shared__ int lcur[RPB];
    const int b    = blockIdx.x;
    const int tid  = threadIdx.x;
    const int base = bbase[b];
    const int cnt  = bbase[b + 1] - base;

    if (tid < RPB) hist[tid] = 0;
    __syncthreads();
    for (int i = tid; i < cnt; i += 256)
        atomicAdd(&hist[binned[base + i].x >> 17], 1);
    __syncthreads();

    // wave 0 scans the 128 histogram entries (two 64-wide shfl scans)
    if (tid < 64) {
        int h0 = hist[tid], h1 = hist[64 + tid];
        int i0 = h0, i1 = h1;
        #pragma unroll
        for (int off = 1; off < 64; off <<= 1) {
            int t0 = __shfl_up(i0, off, 64);
            int t1 = __shfl_up(i1, off, 64);
            if (tid >= off) { i0 += t0; i1 += t1; }
        }
        int tot0 = __shfl(i0, 63, 64);
        lcur[tid]      = i0 - h0;
        lcur[64 + tid] = tot0 + i1 - h1;
    }
    __syncthreads();
    if (tid < RPB) {
        int g = b * RPB + tid;
        if (g < n) row_ptr[g] = base + lcur[tid];
    }
    __syncthreads();
    for (int i = tid; i < cnt; i += 256) {
        int2 p  = binned[base + i];
        int  r7 = p.x >> 17;
        int  off = atomicAdd(&lcur[r7], 1);
        edges[base + off] = make_int2(p.x & 0x1FFFF, p.y);
    }
}

// One wave per row; lane j holds dims [2j, 2j+1] (one __half2 = 4 B/lane).
// mode 0: xout[row] = fp16(s)
// mode 1: out[row]  = (emb[row] + x1[row] + xin[row](=x2) + s) * 0.25  (fp32)
__global__ void __launch_bounds__(256)
lgcn_spmm(const int* __restrict__ row_ptr, const int2* __restrict__ edges,
          const __half2* __restrict__ xin, __half2* __restrict__ xout,
          const float2* __restrict__ emb, const __half2* __restrict__ x1h,
          float2* __restrict__ out, int n, int mode) {
    const int wave = blockIdx.x * 4 + (threadIdx.x >> 6);
    const int lane = threadIdx.x & 63;
    if (wave >= n) return;
    const int beg = row_ptr[wave];
    const int end = row_ptr[wave + 1];

    float sx = 0.f, sy = 0.f;
    int e = beg;
    for (; e + 8 <= end; e += 8) {
        long long q[8];
        #pragma unroll
        for (int k = 0; k < 8; ++k)
            q[k] = __builtin_nontemporal_load((const long long*)(edges + e + k));
        #pragma unroll
        for (int k = 0; k < 8; ++k) {
            int   c = (int)(q[k] & 0xFFFFFFFFll);
            float v = __int_as_float((int)(q[k] >> 32));
            float2 a = __half22float2(xin[c * 64 + lane]);
            sx = fmaf(v, a.x, sx); sy = fmaf(v, a.y, sy);
        }
    }
    for (; e < end; ++e) {
        long long q = __builtin_nontemporal_load((const long long*)(edges + e));
        int   c = (int)(q & 0xFFFFFFFFll);
        float v = __int_as_float((int)(q >> 32));
        float2 a = __half22float2(xin[c * 64 + lane]);
        sx = fmaf(v, a.x, sx); sy = fmaf(v, a.y, sy);
    }

    const int o = wave * 64 + lane;
    if (mode == 0) {
        xout[o] = __float22half2_rn(make_float2(sx, sy));
    } else {
        float2 em = emb[o];
        float2 b1 = __half22float2(x1h[o]);
        float2 b2 = __half22float2(xin[o]);
        out[o] = make_float2((em.x + b1.x + b2.x + sx) * 0.25f,
                             (em.y + b1.y + b2.y + sy) * 0.25f);
    }
}

extern "C" void kernel_launch(void* const* d_in, const int* in_sizes, int n_in,
                              void* d_out, int out_size, void* d_ws, size_t ws_size,
                              hipStream_t stream) {
    const float* emb  = (const float*)d_in[0];
    const int*   rows = (const int*)d_in[1];
    const int*   cols = (const int*)d_in[2];
    const float* vals = (const float*)d_in[3];

    const int  n_nodes = in_sizes[0] / DIM;    // 100000
    const int  nedges  = in_sizes[1];          // 2000000
    const long nd      = (long)n_nodes * DIM;  // 12.8M
    const int  nb      = (n_nodes + RPB - 1) / RPB;  // 782

    char* ws = (char*)d_ws;
    size_t off = 0;
    __half2* bufA = (__half2*)(ws + off); off = align_up(off + nd * 2, 256);   // x0, then x2
    __half2* bufB = (__half2*)(ws + off); off = align_up(off + nd * 2, 256);   // x1
    int2* binned  = (int2*)(ws + off);    off = align_up(off + (size_t)nedges * 8, 256);
    int2* edges   = (int2*)(ws + off);    off = align_up(off + (size_t)nedges * 8, 256);
    int* bcnt     = (int*)(ws + off);     off = align_up(off + (size_t)(nb + 1) * 4, 256);
    int* bbase    = (int*)(ws + off);     off = align_up(off + (size_t)(nb + 1) * 4, 256);
    int* bcursor  = (int*)(ws + off);     off = align_up(off + (size_t)nb * 4, 256);
    int* row_ptr  = (int*)(ws + off);     off = align_up(off + (size_t)(n_nodes + 1) * 4, 256);
    float2* out   = (float2*)d_out;

    const int BS = 256;
    const int grid_e = (nedges + BS - 1) / BS;
    const int n2     = (int)(nd / 2);
    const int grid_c = (n2 + BS - 1) / BS;
    const int grid_s = (n_nodes + 3) / 4;   // 4 rows (waves) per block

    // emb -> fp16 x0 (independent of CSR build)
    lgcn_conv<<<grid_c, BS, 0, stream>>>((const float2*)emb, bufA, n2);

    // Bucketed CSR build
    hipMemsetAsync(bcnt, 0, (size_t)nb * sizeof(int), stream);
    lgcn_bhist<<<1024, BS, 0, stream>>>(rows, bcnt, nedges, nb);
    lgcn_bscan<<<1, 1024, 0, stream>>>(bcnt, bbase, bcursor, row_ptr, nb, n_nodes);
    lgcn_bin<<<grid_e, BS, 0, stream>>>(rows, cols, vals, bcursor, binned, nedges);
    lgcn_csr<<<nb, BS, 0, stream>>>(binned, bbase, row_ptr, edges, n_nodes);

    // 3 SpMM layers: x1 = A x0, x2 = A x1, out = (emb + x1 + x2 + A x2)/4
    lgcn_spmm<<<grid_s, BS, 0, stream>>>(row_ptr, edges, bufA, bufB,
                                         nullptr, nullptr, nullptr, n_nodes, 0);
    lgcn_spmm<<<grid_s, BS, 0, stream>>>(row_ptr, edges, bufB, bufA,
                                         nullptr, nullptr, nullptr, n_nodes, 0);
    lgcn_spmm<<<grid_s, BS, 0, stream>>>(row_ptr, edges, bufA, nullptr,
                                         (const float2*)emb, bufB, out, n_nodes, 1);
}

// Round 5
// 593.279 us; speedup vs baseline: 1.5804x; 1.5804x over previous
//
#include <hip/hip_runtime.h>
#include <hip/hip_fp16.h>

// LightGCN propagation on MI355X — round 5: block-aggregated radix partition.
// N = 100000 nodes, D = 128, E = 2,000,000 edges, 3 layers.
//
// Round-4 regression analysis: per-edge global atomicAdd on 782 bucket
// cursors serialized (~2558 RMWs/address, 471 us), and scattered 8 B stores
// amplified ~6x regardless of tail count because bytes for a line arrive
// spread out in time across waves/XCDs. Round 5 partitions with the classic
// 3-kernel block-aggregated scheme:
//   k1 count : block b = edges [b*8192,(b+1)*8192): LDS hist over 782
//              buckets -> ghist[b][i] (coalesced store, no global atomics)
//   k2 gscan : bucket totals -> exclusive bucket bases (bbase) AND absolute
//              per-(block,bucket) bases written back into ghist
//   k3 scat  : block reloads chunk, LDS-atomic cursors seeded from
//              ghist[b][*], writes each bucket's ~10 edges as one burst ->
//              L2 merges within the block's lifetime, no global atomics.
// Then per-bucket CSR (LDS 128-row hist + wave scan -> row_ptr + row-sorted
// edges), and 3 fp16-gather SpMM layers (one wave/row, 4 B/lane, unroll 8,
// non-temporal edge loads); layer 3 fuses out = (emb + x1 + x2 + A x2)/4.

#define DIM 128
#define RPB 128        // rows per bucket
#define RPB_SHIFT 7
#define CHUNK 8192     // edges per partition block

static inline size_t align_up(size_t v, size_t a) { return (v + a - 1) & ~(a - 1); }

__global__ void lgcn_conv(const float2* __restrict__ emb, __half2* __restrict__ x0,
                          int n2) {
    int i = blockIdx.x * blockDim.x + threadIdx.x;
    if (i < n2) x0[i] = __float22half2_rn(emb[i]);
}

// k1: per-block bucket histogram -> ghist[b][i] (coalesced).
__global__ void __launch_bounds__(256)
lgcn_count(const int* __restrict__ rows, int* __restrict__ ghist,
           int nedges, int nb) {
    __shared__ int h[1024];
    const int tid = threadIdx.x;
    for (int i = tid; i < nb; i += 256) h[i] = 0;
    __syncthreads();
    const int e0 = blockIdx.x * CHUNK;
    const int e1 = min(e0 + CHUNK, nedges);
    for (int e = e0 + tid; e < e1; e += 256)
        atomicAdd(&h[rows[e] >> RPB_SHIFT], 1);
    __syncthreads();
    int* g = ghist + (size_t)blockIdx.x * nb;
    for (int i = tid; i < nb; i += 256) g[i] = h[i];
}

// k2: bucket totals -> exclusive bases; ghist[b][i] -> absolute base for
// block b's run within bucket i. Single 1024-thread block (nb <= 1024).
__global__ void __launch_bounds__(1024)
lgcn_gscan(int* __restrict__ ghist, int* __restrict__ bbase,
           int* __restrict__ row_ptr, int nblk, int nb, int n) {
    __shared__ int wsum[16];
    const int tid  = threadIdx.x;
    const int lane = tid & 63;
    const int wid  = tid >> 6;
    int total = 0;
    if (tid < nb)
        for (int b = 0; b < nblk; ++b) total += ghist[(size_t)b * nb + tid];
    int incl = total;
    #pragma unroll
    for (int off = 1; off < 64; off <<= 1) {
        int t = __shfl_up(incl, off, 64);
        if (lane >= off) incl += t;
    }
    if (lane == 63) wsum[wid] = incl;
    __syncthreads();
    if (wid == 0 && lane < 16) {
        int w = wsum[lane];
        #pragma unroll
        for (int off = 1; off < 16; off <<= 1) {
            int t = __shfl_up(w, off, 64);
            if (lane >= off) w += t;
        }
        wsum[lane] = w;
    }
    __syncthreads();
    int ex = incl - total + ((wid > 0) ? wsum[wid - 1] : 0);
    if (tid < nb) {
        bbase[tid] = ex;
        if (tid == nb - 1) {
            bbase[nb]  = ex + total;
            row_ptr[n] = ex + total;
        }
        int run = ex;
        for (int b = 0; b < nblk; ++b) {
            int t = ghist[(size_t)b * nb + tid];
            ghist[(size_t)b * nb + tid] = run;
            run += t;
        }
    }
}

// k3: scatter into buckets via LDS cursors (no global atomics).
__global__ void __launch_bounds__(256)
lgcn_scat(const int* __restrict__ rows, const int* __restrict__ cols,
          const float* __restrict__ vals, const int* __restrict__ ghist,
          int2* __restrict__ binned, int nedges, int nb) {
    __shared__ int lcur[1024];
    const int tid = threadIdx.x;
    const int* g  = ghist + (size_t)blockIdx.x * nb;
    for (int i = tid; i < nb; i += 256) lcur[i] = g[i];
    __syncthreads();
    const int e0 = blockIdx.x * CHUNK;
    const int e1 = min(e0 + CHUNK, nedges);
    for (int e = e0 + tid; e < e1; e += 256) {
        int r   = rows[e];
        int pos = atomicAdd(&lcur[r >> RPB_SHIFT], 1);
        binned[pos] = make_int2(((r & (RPB - 1)) << 17) | cols[e],
                                __float_as_int(vals[e]));
    }
}

// Per-bucket CSR: LDS 128-row hist + wave scan -> row_ptr + row-sorted edges.
__global__ void __launch_bounds__(256)
lgcn_csr(const int2* __restrict__ binned, const int* __restrict__ bbase,
         int* __restrict__ row_ptr, int2* __restrict__ edges, int n) {
    __shared__ int hist[RPB];
    __shared__ int lcur[RPB];
    const int b    = blockIdx.x;
    const int tid  = threadIdx.x;
    const int base = bbase[b];
    const int cnt  = bbase[b + 1] - base;

    if (tid < RPB) hist[tid] = 0;
    __syncthreads();
    for (int i = tid; i < cnt; i += 256)
        atomicAdd(&hist[binned[base + i].x >> 17], 1);
    __syncthreads();

    if (tid < 64) {
        int h0 = hist[tid], h1 = hist[64 + tid];
        int i0 = h0, i1 = h1;
        #pragma unroll
        for (int off = 1; off < 64; off <<= 1) {
            int t0 = __shfl_up(i0, off, 64);
            int t1 = __shfl_up(i1, off, 64);
            if (tid >= off) { i0 += t0; i1 += t1; }
        }
        int tot0 = __shfl(i0, 63, 64);
        lcur[tid]      = i0 - h0;
        lcur[64 + tid] = tot0 + i1 - h1;
    }
    __syncthreads();
    if (tid < RPB) {
        int g = b * RPB + tid;
        if (g < n) row_ptr[g] = base + lcur[tid];
    }
    __syncthreads();
    for (int i = tid; i < cnt; i += 256) {
        int2 p   = binned[base + i];
        int  r7  = p.x >> 17;
        int  off = atomicAdd(&lcur[r7], 1);
        edges[base + off] = make_int2(p.x & 0x1FFFF, p.y);
    }
}

// One wave per row; lane j holds dims [2j, 2j+1] (one __half2 = 4 B/lane).
// mode 0: xout[row] = fp16(s)
// mode 1: out[row]  = (emb[row] + x1[row] + xin[row](=x2) + s) * 0.25  (fp32)
__global__ void __launch_bounds__(256)
lgcn_spmm(const int* __restrict__ row_ptr, const int2* __restrict__ edges,
          const __half2* __restrict__ xin, __half2* __restrict__ xout,
          const float2* __restrict__ emb, const __half2* __restrict__ x1h,
          float2* __restrict__ out, int n, int mode) {
    const int wave = blockIdx.x * 4 + (threadIdx.x >> 6);
    const int lane = threadIdx.x & 63;
    if (wave >= n) return;
    const int beg = row_ptr[wave];
    const int end = row_ptr[wave + 1];

    float sx = 0.f, sy = 0.f;
    int e = beg;
    for (; e + 8 <= end; e += 8) {
        long long q[8];
        #pragma unroll
        for (int k = 0; k < 8; ++k)
            q[k] = __builtin_nontemporal_load((const long long*)(edges + e + k));
        #pragma unroll
        for (int k = 0; k < 8; ++k) {
            int   c = (int)(q[k] & 0xFFFFFFFFll);
            float v = __int_as_float((int)(q[k] >> 32));
            float2 a = __half22float2(xin[c * 64 + lane]);
            sx = fmaf(v, a.x, sx); sy = fmaf(v, a.y, sy);
        }
    }
    for (; e < end; ++e) {
        long long q = __builtin_nontemporal_load((const long long*)(edges + e));
        int   c = (int)(q & 0xFFFFFFFFll);
        float v = __int_as_float((int)(q >> 32));
        float2 a = __half22float2(xin[c * 64 + lane]);
        sx = fmaf(v, a.x, sx); sy = fmaf(v, a.y, sy);
    }

    const int o = wave * 64 + lane;
    if (mode == 0) {
        xout[o] = __float22half2_rn(make_float2(sx, sy));
    } else {
        float2 em = emb[o];
        float2 b1 = __half22float2(x1h[o]);
        float2 b2 = __half22float2(xin[o]);
        out[o] = make_float2((em.x + b1.x + b2.x + sx) * 0.25f,
                             (em.y + b1.y + b2.y + sy) * 0.25f);
    }
}

extern "C" void kernel_launch(void* const* d_in, const int* in_sizes, int n_in,
                              void* d_out, int out_size, void* d_ws, size_t ws_size,
                              hipStream_t stream) {
    const float* emb  = (const float*)d_in[0];
    const int*   rows = (const int*)d_in[1];
    const int*   cols = (const int*)d_in[2];
    const float* vals = (const float*)d_in[3];

    const int  n_nodes = in_sizes[0] / DIM;            // 100000
    const int  nedges  = in_sizes[1];                  // 2000000
    const long nd      = (long)n_nodes * DIM;          // 12.8M
    const int  nb      = (n_nodes + RPB - 1) / RPB;    // 782
    const int  nblk    = (nedges + CHUNK - 1) / CHUNK; // 245

    char* ws = (char*)d_ws;
    size_t off = 0;
    __half2* bufA = (__half2*)(ws + off); off = align_up(off + nd * 2, 256);   // x0, then x2
    __half2* bufB = (__half2*)(ws + off); off = align_up(off + nd * 2, 256);   // x1
    int2* binned  = (int2*)(ws + off);    off = align_up(off + (size_t)nedges * 8, 256);
    int2* edges   = (int2*)(ws + off);    off = align_up(off + (size_t)nedges * 8, 256);
    int* ghist    = (int*)(ws + off);     off = align_up(off + (size_t)nblk * nb * 4, 256);
    int* bbase    = (int*)(ws + off);     off = align_up(off + (size_t)(nb + 1) * 4, 256);
    int* row_ptr  = (int*)(ws + off);     off = align_up(off + (size_t)(n_nodes + 1) * 4, 256);
    float2* out   = (float2*)d_out;

    const int BS = 256;
    const int n2     = (int)(nd / 2);
    const int grid_c = (n2 + BS - 1) / BS;
    const int grid_s = (n_nodes + 3) / 4;   // 4 rows (waves) per block

    // emb -> fp16 x0 (independent of CSR build)
    lgcn_conv<<<grid_c, BS, 0, stream>>>((const float2*)emb, bufA, n2);

    // Block-aggregated partition + per-bucket CSR
    lgcn_count<<<nblk, BS, 0, stream>>>(rows, ghist, nedges, nb);
    lgcn_gscan<<<1, 1024, 0, stream>>>(ghist, bbase, row_ptr, nblk, nb, n_nodes);
    lgcn_scat<<<nblk, BS, 0, stream>>>(rows, cols, vals, ghist, binned, nedges, nb);
    lgcn_csr<<<nb, BS, 0, stream>>>(binned, bbase, row_ptr, edges, n_nodes);

    // 3 SpMM layers: x1 = A x0, x2 = A x1, out = (emb + x1 + x2 + A x2)/4
    lgcn_spmm<<<grid_s, BS, 0, stream>>>(row_ptr, edges, bufA, bufB,
                                         nullptr, nullptr, nullptr, n_nodes, 0);
    lgcn_spmm<<<grid_s, BS, 0, stream>>>(row_ptr, edges, bufB, bufA,
                                         nullptr, nullptr, nullptr, n_nodes, 0);
    lgcn_spmm<<<grid_s, BS, 0, stream>>>(row_ptr, edges, bufA, nullptr,
                                         (const float2*)emb, bufB, out, n_nodes, 1);
}